// Round 1
// baseline (88.343 us; speedup 1.0000x reference)
//
#include <hip/hip_runtime.h>
#include <hip/hip_bf16.h>

typedef __bf16 bf16x8 __attribute__((ext_vector_type(8)));
typedef float  f32x4  __attribute__((ext_vector_type(4)));

#define C_IN   128
#define C_OUT  128
#define IMG_W  56
#define HW     3136      // 56*56
#define NPOS   64        // output positions per block
#define STAGE  192       // staged positions (64 + 64 halo each side)
#define CHUNKS 49        // 3136 / 64
#define WELEMS (9*128*128)

// ---- tiny pre-kernel: convert weight fp32 -> bf16 into workspace ----
__global__ __launch_bounds__(256) void wcvt_kernel(const float* __restrict__ w,
                                                   __bf16* __restrict__ wb, int n) {
    int i = blockIdx.x * 256 + threadIdx.x;
    if (i < n) wb[i] = (__bf16)w[i];
}

// ---- main conv kernel: implicit GEMM, bf16 MFMA ----
// A = weight[(tap*128+o)][c]  (M=128 oc), B = x patches (K = tap,c ; N = pos)
template<bool WS>
__global__ __launch_bounds__(256) void conv_kernel(const float* __restrict__ x,
                                                   const void* __restrict__ wptr,
                                                   float* __restrict__ out) {
    __shared__ __align__(16) __bf16 xs[STAGE * C_IN];   // 48 KB, [pos][c] swizzled

    const int tid  = threadIdx.x;
    const int lane = tid & 63;
    const int wv   = tid >> 6;          // wave 0..3 -> oc block of 32
    const int bx   = blockIdx.x;
    const int n    = bx / CHUNKS;
    const int p0   = (bx % CHUNKS) * NPOS;

    const float* xn = x + (size_t)n * C_IN * HW;

    // ---- stage x[p0-64, p0+128) x 128ch into LDS as bf16, layout [pos][c],
    //      c-index XOR-swizzled by (pos&7)<<3 (16B granules) ----
    for (int it = 0; it < 12; ++it) {
        int task = it * 4 + wv;          // 48 tasks = 3 pos-blocks x 16 c-groups
        int pb   = task >> 4;            // 0..2
        int cg   = task & 15;            // 0..15 (8 channels each)
        int posl = pb * 64 + lane;       // 0..191
        int g    = p0 - 64 + posl;
        g = min(max(g, 0), HW - 1);      // clamped; garbage only read when masked off
        bf16x8 v;
        #pragma unroll
        for (int j = 0; j < 8; ++j)
            v[j] = (__bf16)xn[(size_t)(cg * 8 + j) * HW + g];
        *(bf16x8*)&xs[posl * C_IN + ((cg * 8) ^ ((posl & 7) << 3))] = v;
    }
    __syncthreads();

    // per-lane output positions (4 B/D fragments along pos)
    int hpos[4], wpos[4];
    #pragma unroll
    for (int pf = 0; pf < 4; ++pf) {
        int p = p0 + pf * 16 + (lane & 15);
        hpos[pf] = p / IMG_W;
        wpos[pf] = p - hpos[pf] * IMG_W;
    }
    const int lq = lane >> 4;

    f32x4 acc[2][4] = {};

    bf16x8 bzero;
    #pragma unroll
    for (int j = 0; j < 8; ++j) bzero[j] = (__bf16)0.0f;

    for (int tap = 0; tap < 9; ++tap) {
        const int dh  = tap / 3 - 1;
        const int dw  = tap - (tap / 3) * 3 - 1;
        const int off = dh * IMG_W + dw;

        bool valid[4]; int pl[4];
        #pragma unroll
        for (int pf = 0; pf < 4; ++pf) {
            valid[pf] = ((unsigned)(hpos[pf] + dh) < 56u) && ((unsigned)(wpos[pf] + dw) < 56u);
            pl[pf] = pf * 16 + (lane & 15) + off + 64;   // LDS pos index, always in [0,192)
        }

        #pragma unroll
        for (int c0 = 0; c0 < 128; c0 += 32) {
            // A fragments: rows = wv*32 + {0..15, 16..31}, k = c0 + 8*lq + r
            bf16x8 a0, a1;
            if (WS) {
                const __bf16* wb = (const __bf16*)wptr;
                const __bf16* r0 = &wb[(size_t)(tap * 128 + wv * 32 + (lane & 15)) * 128 + c0 + 8 * lq];
                a0 = *(const bf16x8*)r0;
                a1 = *(const bf16x8*)(r0 + 16 * 128);
            } else {
                const float* wf = (const float*)wptr;
                const float* r0 = &wf[(size_t)(tap * 128 + wv * 32 + (lane & 15)) * 128 + c0 + 8 * lq];
                const float* r1 = r0 + 16 * 128;
                #pragma unroll
                for (int j = 0; j < 8; ++j) { a0[j] = (__bf16)r0[j]; a1[j] = (__bf16)r1[j]; }
            }

            #pragma unroll
            for (int pf = 0; pf < 4; ++pf) {
                bf16x8 b = *(const bf16x8*)&xs[pl[pf] * C_IN + ((c0 + 8 * lq) ^ ((pl[pf] & 7) << 3))];
                b = valid[pf] ? b : bzero;
                acc[0][pf] = __builtin_amdgcn_mfma_f32_16x16x32_bf16(a0, b, acc[0][pf], 0, 0, 0);
                acc[1][pf] = __builtin_amdgcn_mfma_f32_16x16x32_bf16(a1, b, acc[1][pf], 0, 0, 0);
            }
        }
    }

    // ---- store: D frag lane l -> row oc = 4*lq + r, col pos = lane&15 ----
    float* on = out + (size_t)n * C_OUT * HW;
    #pragma unroll
    for (int f = 0; f < 2; ++f)
        #pragma unroll
        for (int pf = 0; pf < 4; ++pf)
            #pragma unroll
            for (int r = 0; r < 4; ++r) {
                int oc  = wv * 32 + f * 16 + lq * 4 + r;
                int pos = p0 + pf * 16 + (lane & 15);
                on[(size_t)oc * HW + pos] = acc[f][pf][r];
            }
}

extern "C" void kernel_launch(void* const* d_in, const int* in_sizes, int n_in,
                              void* d_out, int out_size, void* d_ws, size_t ws_size,
                              hipStream_t stream) {
    const float* x = (const float*)d_in[0];
    const float* w = (const float*)d_in[1];
    float* out = (float*)d_out;

    const int nblocks = 32 * CHUNKS;   // 1568
    if (ws_size >= (size_t)WELEMS * 2) {
        __bf16* wb = (__bf16*)d_ws;
        wcvt_kernel<<<(WELEMS + 255) / 256, 256, 0, stream>>>(w, wb, WELEMS);
        conv_kernel<true><<<nblocks, 256, 0, stream>>>(x, (const void*)wb, out);
    } else {
        conv_kernel<false><<<nblocks, 256, 0, stream>>>(x, (const void*)w, out);
    }
}